// Round 9
// baseline (369.762 us; speedup 1.0000x reference)
//
#include <hip/hip_runtime.h>
#include <hip/hip_bf16.h>

// WOQ int4-asym (tinygemm) linear: out[64,8192] = x @ dequant(w).T
// dequant: (q - 8)*scale + zp, groups of 128 along K.
//
// R11 = R10 (best: total 366.4, gemm ~103us) with the weight stream
// loaded via inline-asm `global_load_dwordx4 ... sc1 nt` (system scope +
// non-temporal = bypass/stream through L2 AND the Infinity Cache).
// Theory: the per-iteration 1-GiB d_ws poison fill leaves the 256MiB MALL
// fully dirty; allocating weight-read misses each evict+write-back a
// dirty line -> ~512MB true DRAM traffic for a 256MB read -> the ~2.5TB/s
// wall. __builtin_nontemporal_load emits `nt` only (L2 streaming), not
// the MALL-scope bit -> R10's small gain. sc1+nt is the full bypass.
// Safety (rule #18): wq consumers guarded by explicit s_waitcnt vmcnt(0)
// + sched_barrier(0) at stage_write head (same semantics as R10's drain).
// Compiler's counted vmcnt(N) waits for x remain safe: untracked asm
// loads can only cause over-waiting, never under-waiting.
// Everything else R10/R7 verbatim: coalesced weight staging (1KB linear
// per wave instr), dequant-on-stage to XOR-swizzled bf16 LDS, compute
// phase pure LDS+MFMA (lgkm-only), BN=64/KSPLIT=4/512thr/2 blocks/CU,
// one barrier per group, kh-pair LDS reduce + atomicAdd epilogue.

#define OUT_F 8192
#define IN_F  8192
#define M_TOK 64
#define GROUP 128
#define BN    64
#define KSPLIT 4
#define KR    (IN_F / KSPLIT)   // 2048 k per block
#define GROUPS (KR / GROUP)     // 16

typedef short short8 __attribute__((ext_vector_type(8)));
typedef float f32x4  __attribute__((ext_vector_type(4)));
typedef int   int4v  __attribute__((ext_vector_type(4)));

// pack two fp32 -> packed bf16 pair (RNE, v_cvt_pk_bf16_f32)
__device__ __forceinline__ unsigned pk(float lo, float hi) {
    __hip_bfloat162 h = __float22bfloat162_rn(float2{lo, hi});
    unsigned r;
    __builtin_memcpy(&r, &h, sizeof(r));
    return r;
}

__global__ void zero_out(float* __restrict__ p) {
    const int i = (blockIdx.x * 256 + threadIdx.x) * 4;
    *(float4*)(p + i) = float4{0.f, 0.f, 0.f, 0.f};
}

__global__ __launch_bounds__(512, 4)
void woq_gemm(const float* __restrict__ x,
              const int*   __restrict__ qw,
              const float* __restrict__ sz,
              float*       __restrict__ outp) {
    // x tiles (bf16, MFMA frag order, dbuf): 2 x 16 KB
    //   slot = (ks*4+mi)*64 + lane; lane l holds x[mi*16+(l&15)][ks*32+(l>>4)*8..+8]
    // w tiles (bf16 [64 rows][128 k], XOR-swizzled, dbuf): 2 x 16 KB
    __shared__ int lds_x[2][4096];
    __shared__ int lds_w[2][4096];

    const int t    = threadIdx.x;       // 0..511
    const int lane = t & 63;
    const int wv   = t >> 6;            // 0..7
    const int wn   = wv & 3;            // n subtile (16 cols)
    const int kh   = wv >> 2;           // k half of each 128-group
    const int n0   = blockIdx.x * BN;
    const int k0   = blockIdx.y * KR;

    const int nlo  = lane & 15;
    const int quad = lane >> 4;
    const int row  = wn * 16 + nlo;     // tile row (n) this lane consumes
    const int n1   = n0 + row;

    // staging identities: chunk c = i*512 + t; row = c>>5 = i*16+tr; 16B col = kc
    const int tr = t >> 5;              // 0..15
    const int kc = t & 31;              // 0..31

    f32x4 acc[4];
#pragma unroll
    for (int mi = 0; mi < 4; ++mi) acc[mi] = (f32x4){0.f, 0.f, 0.f, 0.f};

    int4v  wq[4];    // staged weights (4 rows, 16 B each, contiguous-in-row)
    float2 sc[4];    // scales for those rows
    float4 xs[4];    // staged x (2 slots x 32 B)

    auto stage_load = [&](int g) {
        const int kg = k0 + g * GROUP;
        // weights: per instr i, wave reads two full 512B row-chunks linearly.
        // sc1+nt: stream through L2 AND MALL (no allocation -> no dirty
        // evict/writeback of the poison-filled LLC).
#pragma unroll
        for (int i = 0; i < 4; ++i) {
            const int r = i * 16 + tr;
            const int* p = qw + (size_t)(n0 + r) * IN_F + kg + kc * 4;
            asm volatile("global_load_dwordx4 %0, %1, off sc1 nt"
                         : "=v"(wq[i]) : "v"(p));
        }
        const int gg = kg >> 7;
#pragma unroll
        for (int i = 0; i < 4; ++i) {
            const int r = i * 16 + tr;
            sc[i] = *(const float2*)(sz + ((size_t)gg * OUT_F + n0 + r) * 2);
        }
        // x tile (L2-resident, keep allocating loads for cross-block reuse)
#pragma unroll
        for (int j = 0; j < 2; ++j) {
            const int slot  = t + 512 * j;
            const int chunk = slot >> 6;
            const int l     = slot & 63;
            const int m     = ((chunk & 3) << 4) + (l & 15);
            const int kk    = ((chunk >> 2) << 5) + ((l >> 4) << 3);
            const float4* p = (const float4*)(x + (size_t)m * IN_F + kg + kk);
            xs[2 * j]     = p[0];
            xs[2 * j + 1] = p[1];
        }
    };

    auto stage_write = [&](int buf) {
        // drain the asm weight loads (and older x loads) before first use;
        // sched_barrier stops MFMA/VALU consumers hoisting above the wait.
        asm volatile("s_waitcnt vmcnt(0)" ::: "memory");
        __builtin_amdgcn_sched_barrier(0);

        int* wb = lds_w[buf];
#pragma unroll
        for (int i = 0; i < 4; ++i) {
            const int r = i * 16 + tr;
            const float s = sc[i].x;
            const float c = fmaf(-8.f, sc[i].x, sc[i].y);
            int2 v;
            v.x = (int)pk(fmaf((float)wq[i].x, s, c), fmaf((float)wq[i].y, s, c));
            v.y = (int)pk(fmaf((float)wq[i].z, s, c), fmaf((float)wq[i].w, s, c));
            const int idx = (r * 64 + kc * 2) ^ ((r & 7) << 2);   // XOR swizzle
            *(int2*)&wb[idx] = v;
        }
        int* xb = lds_x[buf];
#pragma unroll
        for (int j = 0; j < 2; ++j) {
            const int slot = t + 512 * j;
            int4v bv;
            bv.x = (int)pk(xs[2 * j].x,     xs[2 * j].y);
            bv.y = (int)pk(xs[2 * j].z,     xs[2 * j].w);
            bv.z = (int)pk(xs[2 * j + 1].x, xs[2 * j + 1].y);
            bv.w = (int)pk(xs[2 * j + 1].z, xs[2 * j + 1].w);
            *(int4v*)&xb[slot * 4] = bv;
        }
    };

    // prologue: stage group 0
    stage_load(0);
    stage_write(0);
    __syncthreads();

    for (int g = 0; g < GROUPS; ++g) {
        if (g + 1 < GROUPS) stage_load(g + 1);   // global loads fly over compute

        // compute group g: pure LDS + MFMA (no vmcnt dependence)
        const int* xb = lds_x[g & 1];
        const int* wb = lds_w[g & 1];
#pragma unroll
        for (int s = 0; s < 2; ++s) {
            const int ks = kh * 2 + s;
            const int bidx = (row * 64 + ks * 16 + quad * 4) ^ ((row & 7) << 2);
            const short8 b = *(const short8*)&wb[bidx];
            short8 a[4];
#pragma unroll
            for (int mi = 0; mi < 4; ++mi)
                a[mi] = *(const short8*)&xb[((ks * 4 + mi) * 64 + lane) * 4];
#pragma unroll
            for (int mi = 0; mi < 4; ++mi)
                acc[mi] = __builtin_amdgcn_mfma_f32_16x16x32_bf16(a[mi], b, acc[mi], 0, 0, 0);
        }

        if (g + 1 < GROUPS) {
            stage_write((g + 1) & 1);            // drains, writes other buf
            __syncthreads();                     // one barrier per group
        }
    }

    // ---- epilogue: kh-pair reduce via LDS, then atomics ----
    __syncthreads();
    f32x4* redp = (f32x4*)&lds_x[0][0];          // 16 KB scratch (safe: last
    if (kh == 1) {                               // compute used lds_x[1])
#pragma unroll
        for (int mi = 0; mi < 4; ++mi)
            redp[(wn * 4 + mi) * 64 + lane] = acc[mi];
    }
    __syncthreads();
    if (kh == 0) {
#pragma unroll
        for (int mi = 0; mi < 4; ++mi)
            acc[mi] += redp[(wn * 4 + mi) * 64 + lane];
        // C/D layout: col = lane&15 (n), row = quad*4 + r (m within frag)
#pragma unroll
        for (int mi = 0; mi < 4; ++mi)
#pragma unroll
            for (int r = 0; r < 4; ++r)
                atomicAdd(outp + (size_t)(mi * 16 + quad * 4 + r) * OUT_F + n1, acc[mi][r]);
    }
}

extern "C" void kernel_launch(void* const* d_in, const int* in_sizes, int n_in,
                              void* d_out, int out_size, void* d_ws, size_t ws_size,
                              hipStream_t stream) {
    const float* x  = (const float*)d_in[0];
    const int*   qw = (const int*)d_in[1];
    const float* sz = (const float*)d_in[2];
    float* out = (float*)d_out;

    zero_out<<<dim3((M_TOK * OUT_F) / (256 * 4)), 256, 0, stream>>>(out);
    woq_gemm<<<dim3(OUT_F / BN, KSPLIT), 512, 0, stream>>>(x, qw, sz, out);
}